// Round 1
// baseline (1117.993 us; speedup 1.0000x reference)
//
#include <hip/hip_runtime.h>
#include <math.h>

#define HIDC 128
#define OUTC 40
#define BN_EPS 1e-5f
#define SCAN_B 1024

// ---------------- CSR build ----------------
__global__ void count_kernel(const int* __restrict__ dst, int* __restrict__ counts, int E) {
  int e = blockIdx.x * blockDim.x + threadIdx.x;
  if (e < E) atomicAdd(&counts[dst[e]], 1);
}

__global__ void scan_blocks(const int* __restrict__ counts, int* __restrict__ excl,
                            int* __restrict__ blockSums, int N) {
  __shared__ int s[SCAN_B];
  int t = threadIdx.x;
  int i = blockIdx.x * SCAN_B + t;
  int v = (i < N) ? counts[i] : 0;
  s[t] = v; __syncthreads();
  for (int off = 1; off < SCAN_B; off <<= 1) {
    int x = (t >= off) ? s[t - off] : 0;
    __syncthreads();
    s[t] += x;
    __syncthreads();
  }
  if (i < N) excl[i] = s[t] - v;
  if (t == SCAN_B - 1) blockSums[blockIdx.x] = s[t];
}

__global__ void scan_top(int* __restrict__ blockSums, int NB) {
  __shared__ int s[SCAN_B];
  int t = threadIdx.x;
  int v = (t < NB) ? blockSums[t] : 0;
  s[t] = v; __syncthreads();
  for (int off = 1; off < SCAN_B; off <<= 1) {
    int x = (t >= off) ? s[t - off] : 0;
    __syncthreads();
    s[t] += x;
    __syncthreads();
  }
  if (t < NB) blockSums[t] = s[t] - v;  // exclusive
}

__global__ void scan_add(int* __restrict__ excl, const int* __restrict__ blockSums,
                         int* __restrict__ cursor, int N) {
  int i = blockIdx.x * SCAN_B + threadIdx.x;
  if (i < N) {
    int v = excl[i] + blockSums[blockIdx.x];
    excl[i] = v;
    cursor[i] = v;
  }
}

__global__ void dis_kernel(const int* __restrict__ counts, float* __restrict__ dis, int N) {
  int i = blockIdx.x * blockDim.x + threadIdx.x;
  if (i < N) dis[i] = rsqrtf((float)(counts[i] + 1));  // +1 = self-loop; deg >= 1
}

__global__ void fill_csr(const int* __restrict__ src, const int* __restrict__ dst,
                         int* __restrict__ cursor, int* __restrict__ csr_src, int E) {
  int e = blockIdx.x * blockDim.x + threadIdx.x;
  if (e < E) {
    int d = dst[e];
    int pos = atomicAdd(&cursor[d], 1);
    csr_src[pos] = src[e];
  }
}

// ---------------- GEMM: [N,128] x [128,128] ----------------
__global__ __launch_bounds__(256) void gemm128(const float* __restrict__ A,
                                               const float* __restrict__ W,
                                               float* __restrict__ C, int N) {
  __shared__ float Wl[128 * 128];   // 64 KB, whole W resident
  __shared__ float Al[64][33];      // +1 pad breaks bank aliasing
  int t = threadIdx.x;
  for (int idx = t; idx < 128 * 128; idx += 256) Wl[idx] = W[idx];
  int tr = t >> 5;        // 0..7  -> 8-row group
  int tc = t & 31;        // 0..31 -> col (stride-32 cols: conflict-free)
  int rowBase = blockIdx.x * 64;
  float acc[8][4];
  #pragma unroll
  for (int u = 0; u < 8; ++u) { acc[u][0] = 0.f; acc[u][1] = 0.f; acc[u][2] = 0.f; acc[u][3] = 0.f; }

  for (int kt = 0; kt < 128; kt += 32) {
    __syncthreads();  // W ready on first iter; Al reuse safe on later iters
    #pragma unroll
    for (int u = 0; u < 8; ++u) {
      int id = u * 256 + t;
      int r = id >> 5, col = id & 31;
      int gr = rowBase + r;
      Al[r][col] = (gr < N) ? A[(size_t)gr * 128 + kt + col] : 0.f;
    }
    __syncthreads();
    #pragma unroll
    for (int kk = 0; kk < 32; ++kk) {
      int k = kt + kk;
      float w0 = Wl[k * 128 + tc];
      float w1 = Wl[k * 128 + tc + 32];
      float w2 = Wl[k * 128 + tc + 64];
      float w3 = Wl[k * 128 + tc + 96];
      #pragma unroll
      for (int u = 0; u < 8; ++u) {
        float a = Al[tr * 8 + u][kk];
        acc[u][0] += a * w0; acc[u][1] += a * w1; acc[u][2] += a * w2; acc[u][3] += a * w3;
      }
    }
  }
  #pragma unroll
  for (int u = 0; u < 8; ++u) {
    int gr = rowBase + tr * 8 + u;
    if (gr < N) {
      float* cr = C + (size_t)gr * 128;
      cr[tc]      = acc[u][0];
      cr[tc + 32] = acc[u][1];
      cr[tc + 64] = acc[u][2];
      cr[tc + 96] = acc[u][3];
    }
  }
}

// ---------------- GEMM: [N,128] x [128,40] ----------------
__global__ __launch_bounds__(256) void gemm40(const float* __restrict__ A,
                                              const float* __restrict__ W,
                                              float* __restrict__ C, int N) {
  __shared__ float Wl[128 * OUTC];      // 20.5 KB
  __shared__ float Al[256 * 17];        // 17.4 KB, stride 17 -> conflict-free
  int t = threadIdx.x;
  for (int idx = t; idx < 128 * OUTC; idx += 256) Wl[idx] = W[idx];
  int rowBase = blockIdx.x * 256;
  float acc[OUTC];
  #pragma unroll
  for (int c = 0; c < OUTC; ++c) acc[c] = 0.f;

  for (int kt = 0; kt < 128; kt += 16) {
    __syncthreads();
    #pragma unroll
    for (int u = 0; u < 16; ++u) {
      int id = u * 256 + t;
      int r = id >> 4, col = id & 15;
      int gr = rowBase + r;
      Al[r * 17 + col] = (gr < N) ? A[(size_t)gr * 128 + kt + col] : 0.f;
    }
    __syncthreads();
    #pragma unroll
    for (int kk = 0; kk < 16; ++kk) {
      float a = Al[t * 17 + kk];
      const float* wr = &Wl[(kt + kk) * OUTC];
      #pragma unroll
      for (int c = 0; c < OUTC; ++c) acc[c] += a * wr[c];
    }
  }
  int gr = rowBase + t;
  if (gr < N) {
    float* cr = C + (size_t)gr * OUTC;
    #pragma unroll
    for (int c = 0; c < OUTC; ++c) cr[c] = acc[c];
  }
}

// ---------------- aggregation (128 ch): 32 threads/node, float4/thread ----------------
__global__ __launch_bounds__(256) void agg128(const float4* __restrict__ h4,
                                              const float* __restrict__ dis,
                                              const int* __restrict__ rowStart,
                                              const int* __restrict__ counts,
                                              const int* __restrict__ csrSrc,
                                              const float* __restrict__ bias,
                                              float4* __restrict__ out4, int N) {
  int g = threadIdx.x >> 5;          // node within block (0..7)
  int q = threadIdx.x & 31;          // float4 lane (0..31)
  int i = blockIdx.x * 8 + g;
  if (i >= N) return;
  float di = dis[i];
  float wself = di * di;
  float4 acc = h4[(size_t)i * 32 + q];
  acc.x *= wself; acc.y *= wself; acc.z *= wself; acc.w *= wself;
  int s0 = rowStart[i];
  int cnt = counts[i];
  for (int e = 0; e < cnt; ++e) {
    int s = csrSrc[s0 + e];
    float w = dis[s] * di;
    float4 v = h4[(size_t)s * 32 + q];
    acc.x += v.x * w; acc.y += v.y * w; acc.z += v.z * w; acc.w += v.w * w;
  }
  float4 b = ((const float4*)bias)[q];
  acc.x += b.x; acc.y += b.y; acc.z += b.z; acc.w += b.w;
  out4[(size_t)i * 32 + q] = acc;
}

// ---------------- BatchNorm stats: per-channel sum & sumsq ----------------
__global__ __launch_bounds__(256) void bn_stats(const float* __restrict__ h,
                                                float* __restrict__ stats, int N) {
  int c = threadIdx.x & 127;
  int half = threadIdx.x >> 7;   // 0/1 -> two rows in flight per block
  float s = 0.f, s2 = 0.f;
  for (int r = blockIdx.x * 2 + half; r < N; r += gridDim.x * 2) {
    float v = h[(size_t)r * 128 + c];
    s += v; s2 += v * v;
  }
  __shared__ float l1[256], l2[256];
  l1[threadIdx.x] = s; l2[threadIdx.x] = s2;
  __syncthreads();
  if (half == 0) {
    atomicAdd(&stats[c],       s  + l1[c + 128]);
    atomicAdd(&stats[128 + c], s2 + l2[c + 128]);
  }
}

__global__ void bn_scale(float* __restrict__ stats, const float* __restrict__ g,
                         const float* __restrict__ be, float invN) {
  int c = threadIdx.x;  // 128 threads
  float mean = stats[c] * invN;
  float var = stats[128 + c] * invN - mean * mean;
  float sc = g[c] * rsqrtf(var + BN_EPS);
  stats[256 + c] = sc;
  stats[384 + c] = be[c] - mean * sc;
}

__global__ __launch_bounds__(256) void bn_apply(const float4* __restrict__ in,
                                                const float* __restrict__ stats,
                                                float4* __restrict__ out, int n4) {
  int idx = blockIdx.x * blockDim.x + threadIdx.x;
  if (idx >= n4) return;
  int c4 = (idx & 31) * 4;
  const float* sc = stats + 256;
  const float* sh = stats + 384;
  float4 v = in[idx];
  v.x = fmaxf(v.x * sc[c4]     + sh[c4],     0.f);
  v.y = fmaxf(v.y * sc[c4 + 1] + sh[c4 + 1], 0.f);
  v.z = fmaxf(v.z * sc[c4 + 2] + sh[c4 + 2], 0.f);
  v.w = fmaxf(v.w * sc[c4 + 3] + sh[c4 + 3], 0.f);
  out[idx] = v;
}

// ---------------- layer-3 aggregation + bias + softmax (wave per node) ----------------
__global__ __launch_bounds__(256) void agg40_softmax(const float* __restrict__ h,
                                                     const float* __restrict__ dis,
                                                     const int* __restrict__ rowStart,
                                                     const int* __restrict__ counts,
                                                     const int* __restrict__ csrSrc,
                                                     const float* __restrict__ b3,
                                                     float* __restrict__ out, int N) {
  int wave = threadIdx.x >> 6;   // 4 nodes / block
  int lane = threadIdx.x & 63;
  int i = blockIdx.x * 4 + wave;
  if (i >= N) return;           // whole wave exits together
  bool ok = lane < OUTC;
  float di = dis[i];
  float acc = ok ? h[(size_t)i * OUTC + lane] * di * di : 0.f;
  int s0 = rowStart[i];
  int cnt = counts[i];
  for (int e = 0; e < cnt; ++e) {
    int s = csrSrc[s0 + e];
    float w = dis[s] * di;
    if (ok) acc += h[(size_t)s * OUTC + lane] * w;
  }
  float v = ok ? acc + b3[lane] : -1e30f;
  float m = v;
  #pragma unroll
  for (int off = 32; off; off >>= 1) m = fmaxf(m, __shfl_xor(m, off));
  float ex = ok ? __expf(v - m) : 0.f;
  float ssum = ex;
  #pragma unroll
  for (int off = 32; off; off >>= 1) ssum += __shfl_xor(ssum, off);
  if (ok) out[(size_t)i * OUTC + lane] = ex / ssum;
}

// ---------------- launcher ----------------
extern "C" void kernel_launch(void* const* d_in, const int* in_sizes, int n_in,
                              void* d_out, int out_size, void* d_ws, size_t ws_size,
                              hipStream_t stream) {
  const float* x   = (const float*)d_in[0];
  const int*   ei  = (const int*)d_in[1];
  const float* W1  = (const float*)d_in[2];
  const float* b1  = (const float*)d_in[3];
  const float* g1  = (const float*)d_in[4];
  const float* be1 = (const float*)d_in[5];
  const float* W2  = (const float*)d_in[6];
  const float* b2  = (const float*)d_in[7];
  const float* g2  = (const float*)d_in[8];
  const float* be2 = (const float*)d_in[9];
  const float* W3  = (const float*)d_in[10];
  const float* b3  = (const float*)d_in[11];

  const int N = in_sizes[0] / HIDC;
  const int E = in_sizes[1] / 2;
  const int* srcI = ei;
  const int* dstI = ei + E;

  float* outSoft = (float*)d_out;                       // [N,40]
  float* outH    = (float*)d_out + (size_t)N * OUTC;    // [N,128] (2nd output; reused as big temp)

  char* ws = (char*)d_ws;
  size_t off = 0;
  auto alloc = [&](size_t bytes) -> char* {
    char* p = ws + off;
    off += (bytes + 255) & ~(size_t)255;
    return p;
  };
  float* bufA      = (float*)alloc((size_t)N * HIDC * 4);  // GEMM output temp (also [N,40] for L3)
  float* dis       = (float*)alloc((size_t)N * 4);
  float* stats     = (float*)alloc(1024 * 4);              // L1: [0..512), L2: [512..1024)
  int*   counts    = (int*)alloc((size_t)N * 4);
  int*   rowStart  = (int*)alloc((size_t)N * 4);
  int*   cursor    = (int*)alloc((size_t)N * 4);
  int*   blockSums = (int*)alloc(SCAN_B * 4);
  int*   csrSrc    = (int*)alloc((size_t)E * 4);
  (void)ws_size; (void)n_in;

  hipMemsetAsync(counts, 0, (size_t)N * 4, stream);
  hipMemsetAsync(stats, 0, 1024 * 4, stream);

  const int NB = (N + SCAN_B - 1) / SCAN_B;
  count_kernel<<<(E + 255) / 256, 256, 0, stream>>>(dstI, counts, E);
  scan_blocks<<<NB, SCAN_B, 0, stream>>>(counts, rowStart, blockSums, N);
  scan_top<<<1, SCAN_B, 0, stream>>>(blockSums, NB);
  scan_add<<<NB, SCAN_B, 0, stream>>>(rowStart, blockSums, cursor, N);
  dis_kernel<<<(N + 255) / 256, 256, 0, stream>>>(counts, dis, N);
  fill_csr<<<(E + 255) / 256, 256, 0, stream>>>(srcI, dstI, cursor, csrSrc, E);

  const float invN = 1.0f / (float)N;

  // ---- Layer 1: x -> bufA -> outH (agg) -> BN+ReLU in place ----
  gemm128<<<(N + 63) / 64, 256, 0, stream>>>(x, W1, bufA, N);
  agg128<<<(N + 7) / 8, 256, 0, stream>>>((const float4*)bufA, dis, rowStart, counts,
                                          csrSrc, b1, (float4*)outH, N);
  bn_stats<<<256, 256, 0, stream>>>(outH, stats, N);
  bn_scale<<<1, 128, 0, stream>>>(stats, g1, be1, invN);
  bn_apply<<<(N * 32 + 255) / 256, 256, 0, stream>>>((const float4*)outH, stats,
                                                     (float4*)outH, N * 32);

  // ---- Layer 2: outH -> bufA -> outH (agg) -> BN+ReLU in place (this IS output h) ----
  gemm128<<<(N + 63) / 64, 256, 0, stream>>>(outH, W2, bufA, N);
  agg128<<<(N + 7) / 8, 256, 0, stream>>>((const float4*)bufA, dis, rowStart, counts,
                                          csrSrc, b2, (float4*)outH, N);
  bn_stats<<<256, 256, 0, stream>>>(outH, stats + 512, N);
  bn_scale<<<1, 128, 0, stream>>>(stats + 512, g2, be2, invN);
  bn_apply<<<(N * 32 + 255) / 256, 256, 0, stream>>>((const float4*)outH, stats + 512,
                                                     (float4*)outH, N * 32);

  // ---- Layer 3: outH -> bufA [N,40] -> softmax -> outSoft ----
  gemm40<<<(N + 255) / 256, 256, 0, stream>>>(outH, W3, bufA, N);
  agg40_softmax<<<(N + 3) / 4, 256, 0, stream>>>(bufA, dis, rowStart, counts,
                                                 csrSrc, b3, outSoft, N);
}

// Round 2
// 848.857 us; speedup vs baseline: 1.3171x; 1.3171x over previous
//
#include <hip/hip_runtime.h>
#include <math.h>

#define HIDC 128
#define OUTC 40
#define BN_EPS 1e-5f
#define SCAN_B 1024

// ---------------- bf16 helpers ----------------
__device__ __forceinline__ unsigned short f2bf(float f) {
  union { float f; unsigned u; } v; v.f = f;
  unsigned r = v.u + 0x7fff + ((v.u >> 16) & 1);   // RNE
  return (unsigned short)(r >> 16);
}
__device__ __forceinline__ float bf2f(unsigned short h) {
  union { unsigned u; float f; } v; v.u = ((unsigned)h) << 16;
  return v.f;
}

// ---------------- CSR build ----------------
__global__ void count_kernel(const int* __restrict__ dst, int* __restrict__ counts, int E) {
  int e = blockIdx.x * blockDim.x + threadIdx.x;
  if (e < E) atomicAdd(&counts[dst[e]], 1);
}

__global__ void scan_blocks(const int* __restrict__ counts, int* __restrict__ excl,
                            int* __restrict__ blockSums, int N) {
  __shared__ int s[SCAN_B];
  int t = threadIdx.x;
  int i = blockIdx.x * SCAN_B + t;
  int v = (i < N) ? counts[i] : 0;
  s[t] = v; __syncthreads();
  for (int off = 1; off < SCAN_B; off <<= 1) {
    int x = (t >= off) ? s[t - off] : 0;
    __syncthreads();
    s[t] += x;
    __syncthreads();
  }
  if (i < N) excl[i] = s[t] - v;
  if (t == SCAN_B - 1) blockSums[blockIdx.x] = s[t];
}

__global__ void scan_top(int* __restrict__ blockSums, int NB) {
  __shared__ int s[SCAN_B];
  int t = threadIdx.x;
  int v = (t < NB) ? blockSums[t] : 0;
  s[t] = v; __syncthreads();
  for (int off = 1; off < SCAN_B; off <<= 1) {
    int x = (t >= off) ? s[t - off] : 0;
    __syncthreads();
    s[t] += x;
    __syncthreads();
  }
  if (t < NB) blockSums[t] = s[t] - v;  // exclusive
}

__global__ void scan_add(int* __restrict__ excl, const int* __restrict__ blockSums,
                         int* __restrict__ cursor, int N) {
  int i = blockIdx.x * SCAN_B + threadIdx.x;
  if (i < N) {
    int v = excl[i] + blockSums[blockIdx.x];
    excl[i] = v;
    cursor[i] = v;
  }
}

__global__ void dis_kernel(const int* __restrict__ counts, float* __restrict__ dis, int N) {
  int i = blockIdx.x * blockDim.x + threadIdx.x;
  if (i < N) dis[i] = rsqrtf((float)(counts[i] + 1));  // +1 = self-loop
}

__global__ void fill_csr(const int* __restrict__ src, const int* __restrict__ dst,
                         int* __restrict__ cursor, const float* __restrict__ dis,
                         int* __restrict__ csrSrc, float* __restrict__ csrW, int E) {
  int e = blockIdx.x * blockDim.x + threadIdx.x;
  if (e < E) {
    int d = dst[e];
    int s = src[e];
    int pos = atomicAdd(&cursor[d], 1);
    csrSrc[pos] = s;
    csrW[pos] = dis[s];
  }
}

// ---------------- GEMM: [N,128] x [128,128] -> bf16, optional fused BN+ReLU on A ----------------
template<bool BN>
__global__ __launch_bounds__(256) void gemm128(const float* __restrict__ A,
                                               const float* __restrict__ W,
                                               const float* __restrict__ bnsc,
                                               const float* __restrict__ bnsh,
                                               unsigned short* __restrict__ Cbf, int N) {
  __shared__ float Wl[128 * 128];   // 64 KB
  __shared__ float Al[64][33];
  __shared__ float scs[128], shs[128];
  int t = threadIdx.x;
  for (int idx = t; idx < 128 * 128; idx += 256) Wl[idx] = W[idx];
  if (BN && t < 128) { scs[t] = bnsc[t]; shs[t] = bnsh[t]; }
  int tr = t >> 5;        // 0..7
  int tc = t & 31;        // 0..31 -> owns cols 4*tc .. 4*tc+3
  int rowBase = blockIdx.x * 64;
  float4 acc[8];
  #pragma unroll
  for (int u = 0; u < 8; ++u) acc[u] = make_float4(0.f, 0.f, 0.f, 0.f);

  for (int kt = 0; kt < 128; kt += 32) {
    __syncthreads();
    #pragma unroll
    for (int u = 0; u < 8; ++u) {
      int id = u * 256 + t;
      int r = id >> 5, col = id & 31;
      int gr = rowBase + r;
      float v = (gr < N) ? A[(size_t)gr * 128 + kt + col] : 0.f;
      if (BN) v = fmaxf(v * scs[kt + col] + shs[kt + col], 0.f);
      Al[r][col] = v;
    }
    __syncthreads();
    #pragma unroll
    for (int kk = 0; kk < 32; ++kk) {
      float4 wv = *(const float4*)&Wl[(kt + kk) * 128 + 4 * tc];  // ds_read_b128
      #pragma unroll
      for (int u = 0; u < 8; ++u) {
        float a = Al[tr * 8 + u][kk];
        acc[u].x += a * wv.x; acc[u].y += a * wv.y;
        acc[u].z += a * wv.z; acc[u].w += a * wv.w;
      }
    }
  }
  #pragma unroll
  for (int u = 0; u < 8; ++u) {
    int gr = rowBase + tr * 8 + u;
    if (gr < N) {
      ushort4 o;
      o.x = f2bf(acc[u].x); o.y = f2bf(acc[u].y);
      o.z = f2bf(acc[u].z); o.w = f2bf(acc[u].w);
      *(ushort4*)&Cbf[(size_t)gr * 128 + 4 * tc] = o;
    }
  }
}

// ---------------- GEMM: [N,128] x [128,40] -> bf16 ----------------
__global__ __launch_bounds__(256) void gemm40(const float* __restrict__ A,
                                              const float* __restrict__ W,
                                              unsigned short* __restrict__ Cbf, int N) {
  __shared__ float Wl[128 * OUTC];
  __shared__ float Al[256 * 17];
  int t = threadIdx.x;
  for (int idx = t; idx < 128 * OUTC; idx += 256) Wl[idx] = W[idx];
  int rowBase = blockIdx.x * 256;
  float acc[OUTC];
  #pragma unroll
  for (int c = 0; c < OUTC; ++c) acc[c] = 0.f;

  for (int kt = 0; kt < 128; kt += 16) {
    __syncthreads();
    #pragma unroll
    for (int u = 0; u < 16; ++u) {
      int id = u * 256 + t;
      int r = id >> 4, col = id & 15;
      int gr = rowBase + r;
      Al[r * 17 + col] = (gr < N) ? A[(size_t)gr * 128 + kt + col] : 0.f;
    }
    __syncthreads();
    #pragma unroll
    for (int kk = 0; kk < 16; ++kk) {
      float a = Al[t * 17 + kk];
      const float* wr = &Wl[(kt + kk) * OUTC];
      #pragma unroll
      for (int c = 0; c < OUTC; ++c) acc[c] += a * wr[c];
    }
  }
  int gr = rowBase + t;
  if (gr < N) {
    unsigned short* cr = Cbf + (size_t)gr * OUTC;
    #pragma unroll
    for (int c4 = 0; c4 < OUTC; c4 += 4) {
      ushort4 o;
      o.x = f2bf(acc[c4]); o.y = f2bf(acc[c4 + 1]);
      o.z = f2bf(acc[c4 + 2]); o.w = f2bf(acc[c4 + 3]);
      *(ushort4*)&cr[c4] = o;
    }
  }
}

// ---------------- aggregation (128 ch, bf16 source): 32 threads/node ----------------
__global__ __launch_bounds__(256) void agg128(const unsigned short* __restrict__ hb,
                                              const float* __restrict__ dis,
                                              const int* __restrict__ rowStart,
                                              const int* __restrict__ counts,
                                              const int* __restrict__ csrSrc,
                                              const float* __restrict__ csrW,
                                              const float* __restrict__ bias,
                                              float4* __restrict__ out4, int N) {
  int g = threadIdx.x >> 5;
  int q = threadIdx.x & 31;          // owns channels 4q..4q+3
  int i = blockIdx.x * 8 + g;
  if (i >= N) return;
  const ushort4* base = (const ushort4*)hb;  // row = 32 ushort4
  float di = dis[i];
  float wself = di * di;
  ushort4 sv = base[(size_t)i * 32 + q];
  float4 acc;
  acc.x = bf2f(sv.x) * wself; acc.y = bf2f(sv.y) * wself;
  acc.z = bf2f(sv.z) * wself; acc.w = bf2f(sv.w) * wself;
  int s0 = rowStart[i];
  int cnt = counts[i];
  int e = 0;
  for (; e + 1 < cnt; e += 2) {
    int sA = csrSrc[s0 + e], sB = csrSrc[s0 + e + 1];
    float wA = csrW[s0 + e] * di, wB = csrW[s0 + e + 1] * di;
    ushort4 vA = base[(size_t)sA * 32 + q];
    ushort4 vB = base[(size_t)sB * 32 + q];
    acc.x += bf2f(vA.x) * wA; acc.y += bf2f(vA.y) * wA;
    acc.z += bf2f(vA.z) * wA; acc.w += bf2f(vA.w) * wA;
    acc.x += bf2f(vB.x) * wB; acc.y += bf2f(vB.y) * wB;
    acc.z += bf2f(vB.z) * wB; acc.w += bf2f(vB.w) * wB;
  }
  if (e < cnt) {
    int sA = csrSrc[s0 + e];
    float wA = csrW[s0 + e] * di;
    ushort4 vA = base[(size_t)sA * 32 + q];
    acc.x += bf2f(vA.x) * wA; acc.y += bf2f(vA.y) * wA;
    acc.z += bf2f(vA.z) * wA; acc.w += bf2f(vA.w) * wA;
  }
  float4 b = ((const float4*)bias)[q];
  acc.x += b.x; acc.y += b.y; acc.z += b.z; acc.w += b.w;
  out4[(size_t)i * 32 + q] = acc;
}

// ---------------- BatchNorm stats (float4 reads) ----------------
__global__ __launch_bounds__(256) void bn_stats(const float4* __restrict__ h,
                                                float* __restrict__ stats, int N) {
  int t = threadIdx.x;
  int q = t & 31;    // channel quad
  int rg = t >> 5;   // 0..7
  float4 s = make_float4(0.f, 0.f, 0.f, 0.f);
  float4 s2 = make_float4(0.f, 0.f, 0.f, 0.f);
  for (int r = blockIdx.x * 8 + rg; r < N; r += gridDim.x * 8) {
    float4 v = h[(size_t)r * 32 + q];
    s.x += v.x; s.y += v.y; s.z += v.z; s.w += v.w;
    s2.x += v.x * v.x; s2.y += v.y * v.y; s2.z += v.z * v.z; s2.w += v.w * v.w;
  }
  __shared__ float sm[256][8];
  sm[t][0] = s.x; sm[t][1] = s.y; sm[t][2] = s.z; sm[t][3] = s.w;
  sm[t][4] = s2.x; sm[t][5] = s2.y; sm[t][6] = s2.z; sm[t][7] = s2.w;
  __syncthreads();
  if (t < 32) {
    float a[8] = {0.f, 0.f, 0.f, 0.f, 0.f, 0.f, 0.f, 0.f};
    #pragma unroll
    for (int j = 0; j < 8; ++j)
      #pragma unroll
      for (int k = 0; k < 8; ++k) a[k] += sm[t + 32 * j][k];
    #pragma unroll
    for (int k = 0; k < 4; ++k) {
      atomicAdd(&stats[4 * t + k], a[k]);
      atomicAdd(&stats[128 + 4 * t + k], a[4 + k]);
    }
  }
}

__global__ void bn_scale(float* __restrict__ stats, const float* __restrict__ g,
                         const float* __restrict__ be, float invN) {
  int c = threadIdx.x;  // 128 threads
  float mean = stats[c] * invN;
  float var = stats[128 + c] * invN - mean * mean;
  float sc = g[c] * rsqrtf(var + BN_EPS);
  stats[256 + c] = sc;
  stats[384 + c] = be[c] - mean * sc;
}

__global__ __launch_bounds__(256) void bn_apply(const float4* __restrict__ in,
                                                const float* __restrict__ stats,
                                                float4* __restrict__ out, int n4) {
  int idx = blockIdx.x * blockDim.x + threadIdx.x;
  if (idx >= n4) return;
  int c4 = (idx & 31) * 4;
  const float* sc = stats + 256;
  const float* sh = stats + 384;
  float4 v = in[idx];
  v.x = fmaxf(v.x * sc[c4]     + sh[c4],     0.f);
  v.y = fmaxf(v.y * sc[c4 + 1] + sh[c4 + 1], 0.f);
  v.z = fmaxf(v.z * sc[c4 + 2] + sh[c4 + 2], 0.f);
  v.w = fmaxf(v.w * sc[c4 + 3] + sh[c4 + 3], 0.f);
  out[idx] = v;
}

// ---------------- layer-3 aggregation + bias + softmax (16 lanes/node, bf16 source) ----------------
__global__ __launch_bounds__(256) void agg40_softmax(const unsigned short* __restrict__ hb,
                                                     const float* __restrict__ dis,
                                                     const int* __restrict__ rowStart,
                                                     const int* __restrict__ counts,
                                                     const int* __restrict__ csrSrc,
                                                     const float* __restrict__ csrW,
                                                     const float* __restrict__ b3,
                                                     float* __restrict__ out, int N) {
  int l = threadIdx.x & 15;      // lane in 16-group; lanes 0..9 active (10*4 = 40 ch)
  int g = threadIdx.x >> 4;      // 16 nodes/block
  int i = blockIdx.x * 16 + g;
  if (i >= N) return;
  bool act = l < 10;
  float di = dis[i];
  float4 acc = make_float4(0.f, 0.f, 0.f, 0.f);
  if (act) {
    ushort4 sv = *(const ushort4*)&hb[(size_t)i * OUTC + l * 4];
    float w = di * di;
    acc.x = bf2f(sv.x) * w; acc.y = bf2f(sv.y) * w;
    acc.z = bf2f(sv.z) * w; acc.w = bf2f(sv.w) * w;
  }
  int s0 = rowStart[i];
  int cnt = counts[i];
  int e = 0;
  for (; e + 1 < cnt; e += 2) {
    int sA = csrSrc[s0 + e], sB = csrSrc[s0 + e + 1];
    float wA = csrW[s0 + e] * di, wB = csrW[s0 + e + 1] * di;
    if (act) {
      ushort4 vA = *(const ushort4*)&hb[(size_t)sA * OUTC + l * 4];
      ushort4 vB = *(const ushort4*)&hb[(size_t)sB * OUTC + l * 4];
      acc.x += bf2f(vA.x) * wA; acc.y += bf2f(vA.y) * wA;
      acc.z += bf2f(vA.z) * wA; acc.w += bf2f(vA.w) * wA;
      acc.x += bf2f(vB.x) * wB; acc.y += bf2f(vB.y) * wB;
      acc.z += bf2f(vB.z) * wB; acc.w += bf2f(vB.w) * wB;
    }
  }
  if (e < cnt) {
    int sA = csrSrc[s0 + e];
    float wA = csrW[s0 + e] * di;
    if (act) {
      ushort4 vA = *(const ushort4*)&hb[(size_t)sA * OUTC + l * 4];
      acc.x += bf2f(vA.x) * wA; acc.y += bf2f(vA.y) * wA;
      acc.z += bf2f(vA.z) * wA; acc.w += bf2f(vA.w) * wA;
    }
  }
  if (act) {
    float4 b = ((const float4*)b3)[l];
    acc.x += b.x; acc.y += b.y; acc.z += b.z; acc.w += b.w;
  }
  // softmax over 40 channels spread across lanes 0..9 (4 each)
  float m = act ? fmaxf(fmaxf(acc.x, acc.y), fmaxf(acc.z, acc.w)) : -1e30f;
  #pragma unroll
  for (int off = 8; off; off >>= 1) m = fmaxf(m, __shfl_xor(m, off, 16));
  float4 ex = make_float4(0.f, 0.f, 0.f, 0.f);
  float lsum = 0.f;
  if (act) {
    ex.x = __expf(acc.x - m); ex.y = __expf(acc.y - m);
    ex.z = __expf(acc.z - m); ex.w = __expf(acc.w - m);
    lsum = ex.x + ex.y + ex.z + ex.w;
  }
  #pragma unroll
  for (int off = 8; off; off >>= 1) lsum += __shfl_xor(lsum, off, 16);
  if (act) {
    float inv = 1.0f / lsum;
    float4 o;
    o.x = ex.x * inv; o.y = ex.y * inv; o.z = ex.z * inv; o.w = ex.w * inv;
    *(float4*)&out[(size_t)i * OUTC + l * 4] = o;
  }
}

// ---------------- launcher ----------------
extern "C" void kernel_launch(void* const* d_in, const int* in_sizes, int n_in,
                              void* d_out, int out_size, void* d_ws, size_t ws_size,
                              hipStream_t stream) {
  const float* x   = (const float*)d_in[0];
  const int*   ei  = (const int*)d_in[1];
  const float* W1  = (const float*)d_in[2];
  const float* b1  = (const float*)d_in[3];
  const float* g1  = (const float*)d_in[4];
  const float* be1 = (const float*)d_in[5];
  const float* W2  = (const float*)d_in[6];
  const float* b2  = (const float*)d_in[7];
  const float* g2  = (const float*)d_in[8];
  const float* be2 = (const float*)d_in[9];
  const float* W3  = (const float*)d_in[10];
  const float* b3  = (const float*)d_in[11];

  const int N = in_sizes[0] / HIDC;
  const int E = in_sizes[1] / 2;
  const int* srcI = ei;
  const int* dstI = ei + E;

  float* outSoft = (float*)d_out;                       // [N,40]
  float* outH    = (float*)d_out + (size_t)N * OUTC;    // [N,128]; doubles as preBN temp

  char* ws = (char*)d_ws;
  size_t off = 0;
  auto alloc = [&](size_t bytes) -> char* {
    char* p = ws + off;
    off += (bytes + 255) & ~(size_t)255;
    return p;
  };
  unsigned short* bufAbf  = (unsigned short*)alloc((size_t)N * HIDC * 2);  // gemm128 out (bf16)
  unsigned short* buf40bf = (unsigned short*)alloc((size_t)N * OUTC * 2);  // gemm40 out (bf16)
  float* dis       = (float*)alloc((size_t)N * 4);
  float* stats     = (float*)alloc(1024 * 4);
  int*   counts    = (int*)alloc((size_t)N * 4);
  int*   rowStart  = (int*)alloc((size_t)N * 4);
  int*   cursor    = (int*)alloc((size_t)N * 4);
  int*   blockSums = (int*)alloc(SCAN_B * 4);
  int*   csrSrc    = (int*)alloc((size_t)E * 4);
  float* csrW      = (float*)alloc((size_t)E * 4);
  (void)ws_size; (void)n_in;

  hipMemsetAsync(counts, 0, (size_t)N * 4, stream);
  hipMemsetAsync(stats, 0, 1024 * 4, stream);

  const int NB = (N + SCAN_B - 1) / SCAN_B;
  count_kernel<<<(E + 255) / 256, 256, 0, stream>>>(dstI, counts, E);
  scan_blocks<<<NB, SCAN_B, 0, stream>>>(counts, rowStart, blockSums, N);
  scan_top<<<1, SCAN_B, 0, stream>>>(blockSums, NB);
  scan_add<<<NB, SCAN_B, 0, stream>>>(rowStart, blockSums, cursor, N);
  dis_kernel<<<(N + 255) / 256, 256, 0, stream>>>(counts, dis, N);
  fill_csr<<<(E + 255) / 256, 256, 0, stream>>>(srcI, dstI, cursor, dis, csrSrc, csrW, E);

  const float invN = 1.0f / (float)N;

  // ---- Layer 1: x -> bufAbf (bf16) -> outH (preBN fp32) ----
  gemm128<false><<<(N + 63) / 64, 256, 0, stream>>>(x, W1, nullptr, nullptr, bufAbf, N);
  agg128<<<(N + 7) / 8, 256, 0, stream>>>(bufAbf, dis, rowStart, counts, csrSrc, csrW,
                                          b1, (float4*)outH, N);
  bn_stats<<<512, 256, 0, stream>>>((const float4*)outH, stats, N);
  bn_scale<<<1, 128, 0, stream>>>(stats, g1, be1, invN);

  // ---- Layer 2: BN1+ReLU fused into gemm load; agg -> outH (preBN); BN2 in place ----
  gemm128<true><<<(N + 63) / 64, 256, 0, stream>>>(outH, W2, stats + 256, stats + 384,
                                                   bufAbf, N);
  agg128<<<(N + 7) / 8, 256, 0, stream>>>(bufAbf, dis, rowStart, counts, csrSrc, csrW,
                                          b2, (float4*)outH, N);
  bn_stats<<<512, 256, 0, stream>>>((const float4*)outH, stats + 512, N);
  bn_scale<<<1, 128, 0, stream>>>(stats + 512, g2, be2, invN);
  bn_apply<<<(N * 32 + 255) / 256, 256, 0, stream>>>((const float4*)outH, stats + 512,
                                                     (float4*)outH, N * 32);

  // ---- Layer 3: outH -> buf40bf (bf16) -> softmax -> outSoft ----
  gemm40<<<(N + 255) / 256, 256, 0, stream>>>(outH, W3, buf40bf, N);
  agg40_softmax<<<(N + 15) / 16, 256, 0, stream>>>(buf40bf, dis, rowStart, counts,
                                                   csrSrc, csrW, b3, outSoft, N);
}